// Round 1
// baseline (174.922 us; speedup 1.0000x reference)
//
#include <hip/hip_runtime.h>
#include <math.h>

#define N1 512
#define N2 512
#define DIN 1280
#define DD 100
#define HH 20
#define KS 7
#define NPIX (N1*N2)
#define PB 57

// workspace layout in floats
static constexpr size_t WS_AC    = 0;                    // 1024*100 = 102400
static constexpr size_t WS_W2T   = 102400;               // 100*40 -> pad 4096
static constexpr size_t WS_M     = 102400 + 4096;        // 20*512*512 = 5242880
static constexpr size_t WS_CONV  = WS_M + 5242880;       // 262144
static constexpr size_t WS_STATS = WS_CONV + 262144;     // 64 (0..19 sum, 20..39 sumsq, 40/41 conv sum/sumsq)
static constexpr size_t WS_B     = WS_STATS + 64;        // 57*57 = 3249

// ---- repack W2 [20][200] -> w2t [100][40]: w2t[d][h]=W2[h][d], w2t[d][20+h]=W2[h][100+d]
__global__ void kW(const float* __restrict__ W2, float* __restrict__ w2t) {
  int idx = blockIdx.x * 256 + threadIdx.x;
  if (idx >= DD * 2 * HH) return;
  int d = idx / (2 * HH), c = idx % (2 * HH);
  w2t[idx] = (c < HH) ? W2[c * 200 + d] : W2[(c - HH) * 200 + 100 + d];
}

// ---- a/c projection: rows 0..511 = x1@W1^T+b1, rows 512..1023 = x2@W1^T+b1
__global__ __launch_bounds__(128) void kA(const float* __restrict__ x1,
                                          const float* __restrict__ x2,
                                          const float* __restrict__ W1,
                                          const float* __restrict__ b1,
                                          float* __restrict__ ac) {
  __shared__ float4 xs[4][DIN / 4];
  const int rb = blockIdx.x * 4;
  const float4* src = (const float4*)((rb < N1) ? (x1 + (size_t)rb * DIN)
                                                : (x2 + (size_t)(rb - N1) * DIN));
  for (int q = threadIdx.x; q < 4 * (DIN / 4); q += 128)
    xs[q / (DIN / 4)][q % (DIN / 4)] = src[q];
  __syncthreads();
  const int h = threadIdx.x;
  if (h < DD) {
    const float4* wr = (const float4*)(W1 + (size_t)h * DIN);
    const float bv = b1[h];
    float a0 = bv, a1 = bv, a2 = bv, a3 = bv;
    for (int k = 0; k < DIN / 4; ++k) {
      float4 w = wr[k];
      float4 v0 = xs[0][k], v1 = xs[1][k], v2 = xs[2][k], v3 = xs[3][k];
      a0 += w.x*v0.x + w.y*v0.y + w.z*v0.z + w.w*v0.w;
      a1 += w.x*v1.x + w.y*v1.y + w.z*v1.z + w.w*v1.w;
      a2 += w.x*v2.x + w.y*v2.y + w.z*v2.z + w.w*v2.w;
      a3 += w.x*v3.x + w.y*v3.y + w.z*v3.z + w.w*v3.w;
    }
    ac[(size_t)(rb + 0) * DD + h] = a0;
    ac[(size_t)(rb + 1) * DD + h] = a1;
    ac[(size_t)(rb + 2) * DD + h] = a2;
    ac[(size_t)(rb + 3) * DD + h] = a3;
  }
}

// ---- pairwise features + FC2 (raw m, pre-BN) + BN1 stats accumulation
__global__ __launch_bounds__(256) void kB(const float* __restrict__ ac,
                                          const float* __restrict__ w2t,
                                          float* __restrict__ m,
                                          float* __restrict__ stats) {
  __shared__ __align__(16) float sA[16][108];   // stride 108: 16B-aligned rows, low conflicts
  __shared__ __align__(16) float sC[16][108];
  __shared__ float wred[4][2 * HH];
  const int tid = threadIdx.x;
  const int bi = blockIdx.x >> 5, bj = blockIdx.x & 31;
  for (int idx = tid; idx < 16 * DD; idx += 256) {
    int r = idx / DD, d = idx % DD;
    sA[r][d] = ac[(size_t)(bi * 16 + r) * DD + d];
    sC[r][d] = ac[(size_t)(N1 + bj * 16 + r) * DD + d];
  }
  __syncthreads();
  const int ti = tid >> 4, tj = tid & 15;
  float acc[HH];
#pragma unroll
  for (int h = 0; h < HH; ++h) acc[h] = 0.0f;
  const float4* sA4 = (const float4*)(&sA[ti][0]);
  const float4* sC4 = (const float4*)(&sC[tj][0]);
  for (int kq = 0; kq < DD / 4; ++kq) {
    float4 av = sA4[kq], cv = sC4[kq];
    float dif[4] = {fabsf(av.x - cv.x), fabsf(av.y - cv.y),
                    fabsf(av.z - cv.z), fabsf(av.w - cv.w)};
    float prd[4] = {av.x * cv.x, av.y * cv.y, av.z * cv.z, av.w * cv.w};
#pragma unroll
    for (int e = 0; e < 4; ++e) {
      const float* wrow = w2t + (size_t)(kq * 4 + e) * (2 * HH);  // uniform -> s_load
#pragma unroll
      for (int h = 0; h < HH; ++h) {
        acc[h] = fmaf(wrow[h], dif[e], acc[h]);
        acc[h] = fmaf(wrow[HH + h], prd[e], acc[h]);
      }
    }
  }
  const int gi = bi * 16 + ti, gj = bj * 16 + tj;
  const int lane = tid & 63, wv = tid >> 6;
#pragma unroll
  for (int h = 0; h < HH; ++h) {
    m[(size_t)h * NPIX + (size_t)gi * N2 + gj] = acc[h];
    float s = acc[h], q = acc[h] * acc[h];
#pragma unroll
    for (int off = 32; off; off >>= 1) {
      s += __shfl_xor(s, off);
      q += __shfl_xor(q, off);
    }
    if (lane == 0) { wred[wv][h] = s; wred[wv][HH + h] = q; }
  }
  __syncthreads();
  if (tid < 2 * HH) {
    float s = wred[0][tid] + wred[1][tid] + wred[2][tid] + wred[3][tid];
    atomicAdd(&stats[tid], s);
  }
}

// ---- conv 7x7 (20ch -> 1), BN1 applied+relu at staging, accumulate BN2 stats
__global__ __launch_bounds__(256) void kD(const float* __restrict__ m,
                                          const float* __restrict__ bn1g,
                                          const float* __restrict__ bn1b,
                                          const float* __restrict__ cw,
                                          float* __restrict__ convOut,
                                          float* __restrict__ stats) {
  __shared__ float sIn[HH][22][24];
  __shared__ float sScale[HH], sShift[HH];
  __shared__ float wred[4][2];
  const int tid = threadIdx.x;
  if (tid < HH) {
    float s = stats[tid], q = stats[HH + tid];
    float mu = s * (1.0f / NPIX);
    float var = q * (1.0f / NPIX) - mu * mu;
    float rs = 1.0f / sqrtf(var + 1e-5f);
    float g = bn1g[tid] * rs;
    sScale[tid] = g;
    sShift[tid] = bn1b[tid] - mu * g;
  }
  __syncthreads();
  const int by = (blockIdx.x >> 5) * 16, bx = (blockIdx.x & 31) * 16;
  for (int idx = tid; idx < HH * 22 * 22; idx += 256) {
    int ch = idx / 484, rem = idx % 484, iy = rem / 22, ix = rem % 22;
    int gy = by + iy - 3, gx = bx + ix - 3;
    float v = 0.0f;
    if (gy >= 0 && gy < N1 && gx >= 0 && gx < N2)
      v = fmaxf(m[(size_t)ch * NPIX + (size_t)gy * N2 + gx] * sScale[ch] + sShift[ch], 0.0f);
    sIn[ch][iy][ix] = v;
  }
  __syncthreads();
  const int ty = tid >> 4, tx = tid & 15;
  float out = 0.0f;
  for (int ch = 0; ch < HH; ++ch) {
#pragma unroll
    for (int ky = 0; ky < KS; ++ky)
#pragma unroll
      for (int kx = 0; kx < KS; ++kx)
        out = fmaf(sIn[ch][ty + ky][tx + kx], cw[ch * 49 + ky * 7 + kx], out);
  }
  convOut[(size_t)(by + ty) * N2 + (bx + tx)] = out;
  float s = out, q = out * out;
  const int lane = tid & 63, wv = tid >> 6;
#pragma unroll
  for (int off = 32; off; off >>= 1) {
    s += __shfl_xor(s, off);
    q += __shfl_xor(q, off);
  }
  if (lane == 0) { wred[wv][0] = s; wred[wv][1] = q; }
  __syncthreads();
  if (tid < 2) {
    float v = wred[0][tid] + wred[1][tid] + wred[2][tid] + wred[3][tid];
    atomicAdd(&stats[2 * HH + tid], v);
  }
}

// ---- BN2 + sigmoid -> C (d_out[1:])
__global__ __launch_bounds__(256) void kE(const float* __restrict__ convOut,
                                          const float* __restrict__ stats,
                                          const float* __restrict__ bn2g,
                                          const float* __restrict__ bn2b,
                                          float* __restrict__ Cout) {
  const int i = blockIdx.x * 256 + threadIdx.x;
  float s = stats[2 * HH], q = stats[2 * HH + 1];
  float mu = s * (1.0f / NPIX);
  float var = q * (1.0f / NPIX) - mu * mu;
  float rs = 1.0f / sqrtf(var + 1e-5f);
  float g = bn2g[0] * rs;
  float b = bn2b[0] - mu * g;
  float z = convOut[i] * g + b;
  Cout[i] = 1.0f / (1.0f + expf(-z));
}

// ---- maxpool 9x9 stride 9 pad 4 -> B [57][57]
__global__ void kM(const float* __restrict__ C, float* __restrict__ B) {
  int p = blockIdx.x * 256 + threadIdx.x;
  if (p >= PB * PB) return;
  int wy = p / PB, wx = p % PB;
  int y0 = wy * 9 - 4, x0 = wx * 9 - 4;
  float mx = -1e30f;
  for (int dy = 0; dy < 9; ++dy) {
    int y = y0 + dy;
    if (y < 0 || y >= N1) continue;
    for (int dx = 0; dx < 9; ++dx) {
      int x = x0 + dx;
      if (x < 0 || x >= N2) continue;
      mx = fmaxf(mx, C[(size_t)y * N2 + x]);
    }
  }
  B[p] = mx;
}

// ---- per-column mean/std(ddof=1), Q=relu(B-mean-gamma*std), phat -> d_out[0]
__global__ __launch_bounds__(256) void kF(const float* __restrict__ B,
                                          const float* __restrict__ gamma,
                                          float* __restrict__ out0) {
  __shared__ float sB[PB * PB];
  __shared__ float cm[PB], cs[PB];
  __shared__ float r1[4], r2[4];
  const int tid = threadIdx.x;
  for (int i = tid; i < PB * PB; i += 256) sB[i] = B[i];
  __syncthreads();
  if (tid < PB) {
    float s = 0.0f;
    for (int h = 0; h < PB; ++h) s += sB[h * PB + tid];
    float mean = s / (float)PB;
    float v = 0.0f;
    for (int h = 0; h < PB; ++h) { float d = sB[h * PB + tid] - mean; v += d * d; }
    cm[tid] = mean;
    cs[tid] = sqrtf(v / (float)(PB - 1) + 1e-5f);
  }
  __syncthreads();
  const float g = gamma[0];
  float sq = 0.0f, cnt = 0.0f;
  for (int i = tid; i < PB * PB; i += 256) {
    int w = i % PB;
    float qv = sB[i] - cm[w] - g * cs[w];
    if (qv > 0.0f) { sq += qv; cnt += 1.0f; }
  }
#pragma unroll
  for (int off = 32; off; off >>= 1) {
    sq += __shfl_xor(sq, off);
    cnt += __shfl_xor(cnt, off);
  }
  if ((tid & 63) == 0) { r1[tid >> 6] = sq; r2[tid >> 6] = cnt; }
  __syncthreads();
  if (tid == 0) {
    float S = r1[0] + r1[1] + r1[2] + r1[3];
    float Cn = r2[0] + r2[1] + r2[2] + r2[3];
    float phat = S / (Cn + 1.0f);
    float sig = 1.0f / (1.0f + expf(-phat));
    out0[0] = fminf(fmaxf(sig, 0.0f), 1.0f);
  }
}

extern "C" void kernel_launch(void* const* d_in, const int* in_sizes, int n_in,
                              void* d_out, int out_size, void* d_ws, size_t ws_size,
                              hipStream_t stream) {
  const float* x1    = (const float*)d_in[0];
  const float* x2    = (const float*)d_in[1];
  const float* W1    = (const float*)d_in[2];
  const float* b1    = (const float*)d_in[3];
  const float* W2    = (const float*)d_in[4];
  // d_in[5] = b2   : cancels exactly through BN1 (training-mode mean subtraction)
  const float* bn1g  = (const float*)d_in[6];
  const float* bn1b  = (const float*)d_in[7];
  const float* convw = (const float*)d_in[8];
  // d_in[9] = conv_b : cancels exactly through BN2
  const float* bn2g  = (const float*)d_in[10];
  const float* bn2b  = (const float*)d_in[11];
  const float* gamma = (const float*)d_in[12];

  float* ws    = (float*)d_ws;
  float* ac    = ws + WS_AC;
  float* w2t   = ws + WS_W2T;
  float* m     = ws + WS_M;
  float* conv  = ws + WS_CONV;
  float* stats = ws + WS_STATS;
  float* Bp    = ws + WS_B;
  float* out   = (float*)d_out;

  hipMemsetAsync(stats, 0, 64 * sizeof(float), stream);
  kW<<<(DD * 2 * HH + 255) / 256, 256, 0, stream>>>(W2, w2t);
  kA<<<256, 128, 0, stream>>>(x1, x2, W1, b1, ac);
  kB<<<1024, 256, 0, stream>>>(ac, w2t, m, stats);
  kD<<<1024, 256, 0, stream>>>(m, bn1g, bn1b, convw, conv, stats);
  kE<<<1024, 256, 0, stream>>>(conv, stats, bn2g, bn2b, out + 1);
  kM<<<(PB * PB + 255) / 256, 256, 0, stream>>>(out + 1, Bp);
  kF<<<1, 256, 0, stream>>>(Bp, gamma, out);
}